// Round 8
// baseline (1410.180 us; speedup 1.0000x reference)
//
#include <hip/hip_runtime.h>
#include <math.h>

#define N_NODES   100000
#define D_FEAT    128
#define N_EDGES   3200000
#define L_FILTERS 10

#define RPB_LOG   7
#define RPB       128
#define NBUCKETS  ((N_NODES + RPB - 1) >> RPB_LOG)     // 782
#define CHUNK     8192
#define NA_BLOCKS ((N_EDGES + CHUNK - 1) / CHUNK)      // 391

typedef unsigned char  u8;
typedef unsigned int   u32;
typedef unsigned short u16;
typedef unsigned long long u64;
typedef float f32x2 __attribute__((ext_vector_type(2)));

static __device__ __forceinline__ u16 f2bf(float f) {
    u32 u = __float_as_uint(f);
    u32 r = (u + 0x7FFFu + ((u >> 16) & 1u)) >> 16;   // RNE
    return (u16)r;
}
static __device__ __forceinline__ float bf2f(u32 b) {
    return __uint_as_float(b << 16);
}

// ---------------- init: Xbf = bf16(X), Xf8 = fp8(X)  (Xf8 doubles as Zhat_10 = X) -----
__global__ void gpr_init(const float* __restrict__ X,
                         u16* __restrict__ Xbf, u8* __restrict__ Xf8, int n4) {
    int i = blockIdx.x * blockDim.x + threadIdx.x;
    if (i >= n4) return;
    float4 v = ((const float4*)X)[i];
    ushort4 b;
    b.x = f2bf(v.x); b.y = f2bf(v.y); b.z = f2bf(v.z); b.w = f2bf(v.w);
    ((ushort4*)Xbf)[i] = b;
    u32 p01 = __builtin_amdgcn_cvt_pk_fp8_f32(v.x, v.y, 0, false) & 0xFFFFu;
    u32 p23 = __builtin_amdgcn_cvt_pk_fp8_f32(v.z, v.w, 0, false) & 0xFFFFu;
    ((u32*)Xf8)[i] = p01 | (p23 << 16);
}

// ---------------- bucket histogram (LDS-private, 1 global atomic per bucket/block) ----
__global__ __launch_bounds__(256) void gpr_bucket_hist(const int* __restrict__ rows,
                                                       int* __restrict__ bcount) {
    __shared__ int hist[NBUCKETS];
    int t = threadIdx.x;
    for (int i = t; i < NBUCKETS; i += 256) hist[i] = 0;
    __syncthreads();
    int stride = gridDim.x * 256;
    for (int e = blockIdx.x * 256 + t; e < N_EDGES; e += stride)
        atomicAdd(&hist[rows[e] >> RPB_LOG], 1);
    __syncthreads();
    for (int i = t; i < NBUCKETS; i += 256)
        if (hist[i]) atomicAdd(&bcount[i], hist[i]);
}

// ---------------- scan 782 bucket counts (single block) ----------------
__global__ __launch_bounds__(1024) void gpr_bucket_scan(const int* __restrict__ bcount,
                                                        int* __restrict__ bucket_base,
                                                        int* __restrict__ bucket_cursor,
                                                        int* __restrict__ row_ptr) {
    __shared__ int buf[1024];
    int t = threadIdx.x;
    int v = (t < NBUCKETS) ? bcount[t] : 0;
    buf[t] = v; __syncthreads();
    for (int off = 1; off < 1024; off <<= 1) {
        int x = (t >= off) ? buf[t - off] : 0;
        __syncthreads();
        buf[t] += x;
        __syncthreads();
    }
    if (t < NBUCKETS) {
        int ex = buf[t] - v;
        bucket_base[t] = ex;
        bucket_cursor[t] = ex;
    }
    if (t == 0) {
        bucket_base[NBUCKETS] = N_EDGES;
        row_ptr[N_NODES] = N_EDGES;
    }
}

// ---------------- phase A: coarse bin into buckets, coalesced writes ----------------
// pack: val15[34:49) | row17[17:34) | col17[0:17)
__global__ __launch_bounds__(256) void gpr_binA(const int* __restrict__ rows,
                                                const int* __restrict__ cols,
                                                const float* __restrict__ vals,
                                                int* __restrict__ bucket_cursor,
                                                u64* __restrict__ packedA) {
    __shared__ u64 stage[CHUNK];
    __shared__ int hist[NBUCKETS];
    __shared__ int lbase[NBUCKETS];
    __shared__ int lcur[NBUCKETS];
    __shared__ int goff[NBUCKETS];
    __shared__ int psum[256];
    int t = threadIdx.x;
    long long base = (long long)blockIdx.x * CHUNK;
    for (int i = t; i < NBUCKETS; i += 256) hist[i] = 0;
    __syncthreads();
    for (int j = 0; j < CHUNK / 256; ++j) {
        long long e = base + j * 256 + t;
        if (e < N_EDGES) atomicAdd(&hist[rows[e] >> RPB_LOG], 1);
    }
    __syncthreads();
    int s = 0, b0 = t * 4;
    #pragma unroll
    for (int j = 0; j < 4; ++j) { int b = b0 + j; if (b < NBUCKETS) s += hist[b]; }
    psum[t] = s; __syncthreads();
    for (int off = 1; off < 256; off <<= 1) {
        int x = (t >= off) ? psum[t - off] : 0;
        __syncthreads();
        psum[t] += x;
        __syncthreads();
    }
    int run = psum[t] - s;
    #pragma unroll
    for (int j = 0; j < 4; ++j) {
        int b = b0 + j;
        if (b < NBUCKETS) { lbase[b] = run; run += hist[b]; }
    }
    __syncthreads();
    for (int i = t; i < NBUCKETS; i += 256) {
        lcur[i] = lbase[i];
        int g = (hist[i]) ? atomicAdd(&bucket_cursor[i], hist[i]) : 0;
        goff[i] = g - lbase[i];
    }
    __syncthreads();
    for (int j = 0; j < CHUNK / 256; ++j) {
        long long e = base + j * 256 + t;
        if (e < N_EDGES) {
            int r = rows[e];
            u32 vb = (u32)f2bf(vals[e]);
            u64 p = ((u64)vb << 34) | ((u64)(u32)r << 17) | (u64)(u32)cols[e];
            int pos = atomicAdd(&lcur[r >> RPB_LOG], 1);
            stage[pos] = p;
        }
    }
    __syncthreads();
    long long rem = (long long)N_EDGES - base;
    int total = (rem < CHUNK) ? (int)rem : CHUNK;
    for (int idx = t; idx < total; idx += 256) {
        u64 p = stage[idx];
        int b = (int)((p >> 17) & 0x1FFFFu) >> RPB_LOG;
        packedA[goff[b] + idx] = p;
    }
}

// ---------------- phase B: per-bucket row histogram + scan + row_ptr + fine scatter ----
__global__ __launch_bounds__(256) void gpr_binB(const int* __restrict__ bucket_base,
                                                const u64* __restrict__ packedA,
                                                int* __restrict__ row_ptr,
                                                u32* __restrict__ edges) {
    __shared__ int cnt[RPB];
    __shared__ int sbuf[RPB];
    __shared__ int cur[RPB];
    int b = blockIdx.x;
    int t = threadIdx.x;
    int r0 = b << RPB_LOG;
    int r1 = r0 + RPB; if (r1 > N_NODES) r1 = N_NODES;
    int lo = bucket_base[b], hi = bucket_base[b + 1];
    if (t < RPB) cnt[t] = 0;
    __syncthreads();
    for (int e = lo + t; e < hi; e += 256) {
        int r = (int)((packedA[e] >> 17) & 0x1FFFFu);
        atomicAdd(&cnt[r - r0], 1);
    }
    __syncthreads();
    if (t < RPB) sbuf[t] = cnt[t];
    __syncthreads();
    for (int off = 1; off < RPB; off <<= 1) {
        int x = (t < RPB && t >= off) ? sbuf[t - off] : 0;
        __syncthreads();
        if (t < RPB) sbuf[t] += x;
        __syncthreads();
    }
    if (t < RPB) {
        int ex = sbuf[t] - cnt[t];
        cur[t] = ex;
        if (r0 + t < r1) row_ptr[r0 + t] = lo + ex;
    }
    __syncthreads();
    for (int e = lo + t; e < hi; e += 256) {
        u64 p = packedA[e];
        int r = (int)((p >> 17) & 0x1FFFFu);
        int pos = lo + atomicAdd(&cur[r - r0], 1);
        edges[pos] = (u32)(((p >> 34) << 17) | (p & 0x1FFFFu));
    }
}

// ---------------- Horner SpMM on normalized fp8 states ----------------
// Zhat_l = X + (w[l+1]/w[l]) * A * Zhat_{l+1}   (WR 0 = fp8 state out, 2 = f32 final)
// final:  out = w0*X + w1 * A * Zhat_1
//
// Structure: one wave per TWO consecutive rows, 2 feats/lane.
// Inner loop = explicit load/compute 16-edge phases, interleaved across the two
// rows: L16(r0) L16(r1) C16(r0) C16(r1) -> up to 32 outstanding 128-B gathers
// per wave (2x round-7's ~8-deep consume-as-you-go). Gather address = SGPR
// base + one v_lshl_add VGPR offset (col<<7 | lane*2). Edge words broadcast
// via v_readlane (re-read in compute phase -> no vv[] register array).
// Tail edges clamp to the row's last edge (hot line) and contribute v = 0.

#define LOAD16(EW, M, TT, HH)                                                  \
    { _Pragma("unroll")                                                        \
      for (int j = 0; j < 16; ++j) {                                           \
          int t = (TT) + j;                                                    \
          int tc = (t < (M)) ? t : ((M) - 1);                                  \
          u32 es = (u32)__builtin_amdgcn_readlane((int)(EW), tc);              \
          HH[j] = *(const u16*)((const u8*)H8 + (size_t)((es & 0x1FFFFu) << 7) + lane2); \
      } }

#define COMP16(EW, M, TT, HH, PX, PY)                                          \
    { _Pragma("unroll")                                                        \
      for (int j = 0; j < 16; ++j) {                                           \
          int t = (TT) + j;                                                    \
          int tc = (t < (M)) ? t : ((M) - 1);                                  \
          u32 es = (u32)__builtin_amdgcn_readlane((int)(EW), tc);              \
          float v = (t < (M)) ? __uint_as_float((es >> 17) << 16) : 0.0f;      \
          f32x2 f = __builtin_amdgcn_cvt_pk_f32_fp8(HH[j], false);             \
          PX[j & 1] = fmaf(v, f[0], PX[j & 1]);                                \
          PY[j & 1] = fmaf(v, f[1], PY[j & 1]);                                \
      } }

template<int WR>
__global__ __launch_bounds__(256) void gpr_spmm(
    const int* __restrict__ row_ptr, const u32* __restrict__ edges,
    const void* __restrict__ Zold, const u16* __restrict__ Xbf,
    const float* __restrict__ Xf, const float* __restrict__ w, int l,
    void* __restrict__ Znew, float* __restrict__ out) {
    int pr = (int)(blockIdx.x * 4 + (threadIdx.x >> 6));
    pr = __builtin_amdgcn_readfirstlane(pr);
    if (pr >= N_NODES / 2) return;
    int row0 = pr * 2;
    int lane = threadIdx.x & 63;
    int lane2 = lane * 2;
    int s0 = __builtin_amdgcn_readfirstlane(row_ptr[row0]);
    int e0 = __builtin_amdgcn_readfirstlane(row_ptr[row0 + 1]);
    int e1 = __builtin_amdgcn_readfirstlane(row_ptr[row0 + 2]);
    int len0 = e0 - s0, len1 = e1 - e0;
    int m0 = (len0 < 64) ? len0 : 64;
    int m1 = (len1 < 64) ? len1 : 64;

    const u16* H8 = (const u16*)Zold;    // fp8 row-major: 2 fp8 feats per u16, 128 B/row

    // issue both rows' first edge-chunks up-front (independent loads)
    u32 ew0 = 0, ew1 = 0;
    if (m0 > 0) { int tc = (lane < m0) ? lane : (m0 - 1); ew0 = edges[s0 + tc]; }
    if (m1 > 0) { int tc = (lane < m1) ? lane : (m1 - 1); ew1 = edges[e0 + tc]; }

    float ax[2] = {0.f, 0.f}, ay[2] = {0.f, 0.f};
    float bx[2] = {0.f, 0.f}, by[2] = {0.f, 0.f};
    u32 hh0[16], hh1[16];

    int mmax = (m0 > m1) ? m0 : m1;
    for (int TT = 0; TT < mmax; TT += 16) {
        if (TT < m0) LOAD16(ew0, m0, TT, hh0)
        if (TT < m1) LOAD16(ew1, m1, TT, hh1)
        if (TT < m0) COMP16(ew0, m0, TT, hh0, ax, ay)
        if (TT < m1) COMP16(ew1, m1, TT, hh1, bx, by)
    }

    // rare long-row chunks (P(len>64) ~ 0 at Poisson(32))
    for (int t0 = 64; t0 < len0; t0 += 64) {
        int rem = len0 - t0;
        int mm = (rem < 64) ? rem : 64;
        int tcl = (lane < mm) ? lane : (mm - 1);
        u32 ew = edges[s0 + t0 + tcl];
        for (int TT = 0; TT < mm; TT += 16) {
            LOAD16(ew, mm, TT, hh0)
            COMP16(ew, mm, TT, hh0, ax, ay)
        }
    }
    for (int t0 = 64; t0 < len1; t0 += 64) {
        int rem = len1 - t0;
        int mm = (rem < 64) ? rem : 64;
        int tcl = (lane < mm) ? lane : (mm - 1);
        u32 ew = edges[e0 + t0 + tcl];
        for (int TT = 0; TT < mm; TT += 16) {
            LOAD16(ew, mm, TT, hh1)
            COMP16(ew, mm, TT, hh1, bx, by)
        }
    }

    float axs = ax[0] + ax[1];
    float ays = ay[0] + ay[1];
    float bxs = bx[0] + bx[1];
    float bys = by[0] + by[1];
    if (!isfinite(axs)) axs = 0.0f;
    if (!isfinite(ays)) ays = 0.0f;
    if (!isfinite(bxs)) bxs = 0.0f;
    if (!isfinite(bys)) bys = 0.0f;

    size_t o0 = (size_t)row0 * 64 + lane;
    size_t o1 = o0 + 64;
    if (WR == 2) {
        float w0 = w[0], w1 = w[1];
        float2 xv0 = ((const float2*)Xf)[o0];
        float2 xv1 = ((const float2*)Xf)[o1];
        f32x2 r0, r1;
        r0[0] = fmaf(w1, axs, w0 * xv0.x);
        r0[1] = fmaf(w1, ays, w0 * xv0.y);
        r1[0] = fmaf(w1, bxs, w0 * xv1.x);
        r1[1] = fmaf(w1, bys, w0 * xv1.y);
        __builtin_nontemporal_store(r0, &((f32x2*)out)[o0]);
        __builtin_nontemporal_store(r1, &((f32x2*)out)[o1]);
    } else {
        float cc = w[l + 1] / w[l];
        u32 xb0 = __builtin_nontemporal_load((const u32*)Xbf + o0);
        u32 xb1 = __builtin_nontemporal_load((const u32*)Xbf + o1);
        float z0x = fmaf(cc, axs, bf2f(xb0 & 0xFFFFu));
        float z0y = fmaf(cc, ays, bf2f(xb0 >> 16));
        float z1x = fmaf(cc, bxs, bf2f(xb1 & 0xFFFFu));
        float z1y = fmaf(cc, bys, bf2f(xb1 >> 16));
        u32 p0 = __builtin_amdgcn_cvt_pk_fp8_f32(z0x, z0y, 0, false);
        u32 p1 = __builtin_amdgcn_cvt_pk_fp8_f32(z1x, z1y, 0, false);
        __builtin_nontemporal_store((u16)p0, (u16*)Znew + o0);
        __builtin_nontemporal_store((u16)p1, (u16*)Znew + o1);
    }
}

extern "C" void kernel_launch(void* const* d_in, const int* in_sizes, int n_in,
                              void* d_out, int out_size, void* d_ws, size_t ws_size,
                              hipStream_t stream) {
    const int*   erow  = (const int*)d_in[0];
    const int*   ecol  = (const int*)d_in[1];
    const float* evals = (const float*)d_in[2];
    const float* X     = (const float*)d_in[3];
    const float* w     = (const float*)d_in[4];
    float* out = (float*)d_out;

    const size_t n = (size_t)N_NODES * D_FEAT;  // 12.8M elements

    // workspace layout (~90 MB)
    char* base = (char*)d_ws;
    u8*  Za      = (u8*)base;                   // fp8, n bytes (init: Zhat_10 = fp8(X))
    u8*  Zb      = (u8*)(base + n);             // fp8, n bytes
    u16* Xbf     = (u16*)(base + 2 * n);        // bf16, 2n bytes
    u64* packedA = (u64*)(base + 4 * n);        // 3.2M u64 = 25.6 MB, dead after binB
    int* row_ptr = (int*)(base + 6 * n);        // 100001 (padded 100352)
    int* bucket_base   = row_ptr + 100352;
    int* bucket_cursor = bucket_base + 1024;
    int* bcount        = bucket_cursor + 1024;
    u32* edges   = (u32*)(bcount + 1024);       // 3.2M u32 = 12.8 MB

    dim3 b256(256);

    // CSR build
    hipMemsetAsync(bcount, 0, NBUCKETS * sizeof(int), stream);
    gpr_bucket_hist<<<dim3(512), b256, 0, stream>>>(erow, bcount);
    gpr_bucket_scan<<<dim3(1), dim3(1024), 0, stream>>>(bcount, bucket_base, bucket_cursor, row_ptr);
    gpr_binA<<<dim3(NA_BLOCKS), b256, 0, stream>>>(erow, ecol, evals, bucket_cursor, packedA);
    gpr_binB<<<dim3(NBUCKETS), b256, 0, stream>>>(bucket_base, packedA, row_ptr, edges);

    // Xbf = bf16(X), Za = fp8(X) = Zhat_10
    gpr_init<<<dim3((unsigned)((n / 4 + 255) / 256)), b256, 0, stream>>>(X, Xbf, Za, (int)(n / 4));

    dim3 spmm_grid((N_NODES / 2 + 3) / 4);      // 12500 blocks, 2 rows/wave
    // hops k = 9..1: fp8 -> fp8
    const void* Zold = Za;
    for (int k = L_FILTERS - 1; k >= 1; --k) {
        void* Znew = (Zold == (void*)Za) ? (void*)Zb : (void*)Za;
        gpr_spmm<0><<<spmm_grid, b256, 0, stream>>>(row_ptr, edges, Zold, Xbf, X, w, k, Znew, nullptr);
        Zold = Znew;
    }
    // hop k = 0 (final): fp8 -> fp32 out = w0*X + w1 * A * Zhat_1
    gpr_spmm<2><<<spmm_grid, b256, 0, stream>>>(row_ptr, edges, Zold, Xbf, X, w, 0, nullptr, out);
}

// Round 9
// 938.154 us; speedup vs baseline: 1.5031x; 1.5031x over previous
//
#include <hip/hip_runtime.h>
#include <math.h>

#define N_NODES   100000
#define D_FEAT    128
#define N_EDGES   3200000
#define L_FILTERS 10

#define RPB_LOG   7
#define RPB       128
#define NBUCKETS  ((N_NODES + RPB - 1) >> RPB_LOG)     // 782
#define CHUNK     8192
#define NA_BLOCKS ((N_EDGES + CHUNK - 1) / CHUNK)      // 391

typedef unsigned char  u8;
typedef unsigned int   u32;
typedef unsigned short u16;
typedef unsigned long long u64;
typedef float f32x2 __attribute__((ext_vector_type(2)));

static __device__ __forceinline__ u16 f2bf(float f) {
    u32 u = __float_as_uint(f);
    u32 r = (u + 0x7FFFu + ((u >> 16) & 1u)) >> 16;   // RNE
    return (u16)r;
}
static __device__ __forceinline__ float bf2f(u32 b) {
    return __uint_as_float(b << 16);
}

// ---------------- init: Xbf = bf16(X), Xf8 = fp8(X)  (Xf8 doubles as Zhat_10 = X) -----
__global__ void gpr_init(const float* __restrict__ X,
                         u16* __restrict__ Xbf, u8* __restrict__ Xf8, int n4) {
    int i = blockIdx.x * blockDim.x + threadIdx.x;
    if (i >= n4) return;
    float4 v = ((const float4*)X)[i];
    ushort4 b;
    b.x = f2bf(v.x); b.y = f2bf(v.y); b.z = f2bf(v.z); b.w = f2bf(v.w);
    ((ushort4*)Xbf)[i] = b;
    u32 p01 = __builtin_amdgcn_cvt_pk_fp8_f32(v.x, v.y, 0, false) & 0xFFFFu;
    u32 p23 = __builtin_amdgcn_cvt_pk_fp8_f32(v.z, v.w, 0, false) & 0xFFFFu;
    ((u32*)Xf8)[i] = p01 | (p23 << 16);
}

// ---------------- bucket histogram (LDS-private, 1 global atomic per bucket/block) ----
__global__ __launch_bounds__(256) void gpr_bucket_hist(const int* __restrict__ rows,
                                                       int* __restrict__ bcount) {
    __shared__ int hist[NBUCKETS];
    int t = threadIdx.x;
    for (int i = t; i < NBUCKETS; i += 256) hist[i] = 0;
    __syncthreads();
    int stride = gridDim.x * 256;
    for (int e = blockIdx.x * 256 + t; e < N_EDGES; e += stride)
        atomicAdd(&hist[rows[e] >> RPB_LOG], 1);
    __syncthreads();
    for (int i = t; i < NBUCKETS; i += 256)
        if (hist[i]) atomicAdd(&bcount[i], hist[i]);
}

// ---------------- scan 782 bucket counts (single block) ----------------
__global__ __launch_bounds__(1024) void gpr_bucket_scan(const int* __restrict__ bcount,
                                                        int* __restrict__ bucket_base,
                                                        int* __restrict__ bucket_cursor,
                                                        int* __restrict__ row_ptr) {
    __shared__ int buf[1024];
    int t = threadIdx.x;
    int v = (t < NBUCKETS) ? bcount[t] : 0;
    buf[t] = v; __syncthreads();
    for (int off = 1; off < 1024; off <<= 1) {
        int x = (t >= off) ? buf[t - off] : 0;
        __syncthreads();
        buf[t] += x;
        __syncthreads();
    }
    if (t < NBUCKETS) {
        int ex = buf[t] - v;
        bucket_base[t] = ex;
        bucket_cursor[t] = ex;
    }
    if (t == 0) {
        bucket_base[NBUCKETS] = N_EDGES;
        row_ptr[N_NODES] = N_EDGES;
    }
}

// ---------------- phase A: coarse bin into buckets, coalesced writes ----------------
// pack: val15[34:49) | row17[17:34) | col17[0:17)
__global__ __launch_bounds__(256) void gpr_binA(const int* __restrict__ rows,
                                                const int* __restrict__ cols,
                                                const float* __restrict__ vals,
                                                int* __restrict__ bucket_cursor,
                                                u64* __restrict__ packedA) {
    __shared__ u64 stage[CHUNK];
    __shared__ int hist[NBUCKETS];
    __shared__ int lbase[NBUCKETS];
    __shared__ int lcur[NBUCKETS];
    __shared__ int goff[NBUCKETS];
    __shared__ int psum[256];
    int t = threadIdx.x;
    long long base = (long long)blockIdx.x * CHUNK;
    for (int i = t; i < NBUCKETS; i += 256) hist[i] = 0;
    __syncthreads();
    for (int j = 0; j < CHUNK / 256; ++j) {
        long long e = base + j * 256 + t;
        if (e < N_EDGES) atomicAdd(&hist[rows[e] >> RPB_LOG], 1);
    }
    __syncthreads();
    int s = 0, b0 = t * 4;
    #pragma unroll
    for (int j = 0; j < 4; ++j) { int b = b0 + j; if (b < NBUCKETS) s += hist[b]; }
    psum[t] = s; __syncthreads();
    for (int off = 1; off < 256; off <<= 1) {
        int x = (t >= off) ? psum[t - off] : 0;
        __syncthreads();
        psum[t] += x;
        __syncthreads();
    }
    int run = psum[t] - s;
    #pragma unroll
    for (int j = 0; j < 4; ++j) {
        int b = b0 + j;
        if (b < NBUCKETS) { lbase[b] = run; run += hist[b]; }
    }
    __syncthreads();
    for (int i = t; i < NBUCKETS; i += 256) {
        lcur[i] = lbase[i];
        int g = (hist[i]) ? atomicAdd(&bucket_cursor[i], hist[i]) : 0;
        goff[i] = g - lbase[i];
    }
    __syncthreads();
    for (int j = 0; j < CHUNK / 256; ++j) {
        long long e = base + j * 256 + t;
        if (e < N_EDGES) {
            int r = rows[e];
            u32 vb = (u32)f2bf(vals[e]);
            u64 p = ((u64)vb << 34) | ((u64)(u32)r << 17) | (u64)(u32)cols[e];
            int pos = atomicAdd(&lcur[r >> RPB_LOG], 1);
            stage[pos] = p;
        }
    }
    __syncthreads();
    long long rem = (long long)N_EDGES - base;
    int total = (rem < CHUNK) ? (int)rem : CHUNK;
    for (int idx = t; idx < total; idx += 256) {
        u64 p = stage[idx];
        int b = (int)((p >> 17) & 0x1FFFFu) >> RPB_LOG;
        packedA[goff[b] + idx] = p;
    }
}

// ---------------- phase B: per-bucket row histogram + scan + row_ptr + fine scatter ----
__global__ __launch_bounds__(256) void gpr_binB(const int* __restrict__ bucket_base,
                                                const u64* __restrict__ packedA,
                                                int* __restrict__ row_ptr,
                                                u32* __restrict__ edges) {
    __shared__ int cnt[RPB];
    __shared__ int sbuf[RPB];
    __shared__ int cur[RPB];
    int b = blockIdx.x;
    int t = threadIdx.x;
    int r0 = b << RPB_LOG;
    int r1 = r0 + RPB; if (r1 > N_NODES) r1 = N_NODES;
    int lo = bucket_base[b], hi = bucket_base[b + 1];
    if (t < RPB) cnt[t] = 0;
    __syncthreads();
    for (int e = lo + t; e < hi; e += 256) {
        int r = (int)((packedA[e] >> 17) & 0x1FFFFu);
        atomicAdd(&cnt[r - r0], 1);
    }
    __syncthreads();
    if (t < RPB) sbuf[t] = cnt[t];
    __syncthreads();
    for (int off = 1; off < RPB; off <<= 1) {
        int x = (t < RPB && t >= off) ? sbuf[t - off] : 0;
        __syncthreads();
        if (t < RPB) sbuf[t] += x;
        __syncthreads();
    }
    if (t < RPB) {
        int ex = sbuf[t] - cnt[t];
        cur[t] = ex;
        if (r0 + t < r1) row_ptr[r0 + t] = lo + ex;
    }
    __syncthreads();
    for (int e = lo + t; e < hi; e += 256) {
        u64 p = packedA[e];
        int r = (int)((p >> 17) & 0x1FFFFu);
        int pos = lo + atomicAdd(&cur[r - r0], 1);
        edges[pos] = (u32)(((p >> 34) << 17) | (p & 0x1FFFFu));
    }
}

// ---------------- Horner SpMM on normalized fp8 states ----------------
// Zhat_l = X + (w[l+1]/w[l]) * A * Zhat_{l+1}   (WR 0 = fp8 state out, 2 = f32 final)
// final:  out = w0*X + w1 * A * Zhat_1
//
// Structure: one wave per TWO consecutive rows, 2 feats/lane (round-7 form).
// One uniform row_ptr read gives all 3 offsets; both rows' 64-edge chunks
// issued up-front. Edge words broadcast via v_readlane (SGPR); gather = SGPR
// base + lane offset. Inner loop: consume-as-you-go batches of SIXTEEN
// independent gathers (vs round-7's 8) with 4 acc chains — compiler issues all
// 16 before the first consume, halving latency-exposed batch boundaries.
// (Round-8 lesson: do NOT stage into explicit register arrays — VGPR blowup
// halves occupancy. Keep the tight per-edge body; let the compiler schedule.)
// Tail edges clamp to the row's last edge (hot line) and contribute v = 0.
template<int WR>
__global__ __launch_bounds__(256) void gpr_spmm(
    const int* __restrict__ row_ptr, const u32* __restrict__ edges,
    const void* __restrict__ Zold, const u16* __restrict__ Xbf,
    const float* __restrict__ Xf, const float* __restrict__ w, int l,
    void* __restrict__ Znew, float* __restrict__ out) {
    int pr = (int)(blockIdx.x * 4 + (threadIdx.x >> 6));
    pr = __builtin_amdgcn_readfirstlane(pr);
    if (pr >= N_NODES / 2) return;
    int row0 = pr * 2;
    int lane = threadIdx.x & 63;
    int s0 = __builtin_amdgcn_readfirstlane(row_ptr[row0]);
    int e0 = __builtin_amdgcn_readfirstlane(row_ptr[row0 + 1]);
    int e1 = __builtin_amdgcn_readfirstlane(row_ptr[row0 + 2]);
    int len0 = e0 - s0, len1 = e1 - e0;
    int m0 = (len0 < 64) ? len0 : 64;
    int m1 = (len1 < 64) ? len1 : 64;

    const u16* H8 = (const u16*)Zold;    // fp8 row-major: 2 fp8 feats per u16

    // issue both rows' first edge-chunks up-front (independent loads)
    u32 ew0 = 0, ew1 = 0;
    if (m0 > 0) { int tc = (lane < m0) ? lane : (m0 - 1); ew0 = edges[s0 + tc]; }
    if (m1 > 0) { int tc = (lane < m1) ? lane : (m1 - 1); ew1 = edges[e0 + tc]; }

    float ax[4] = {0.f,0.f,0.f,0.f}, ay[4] = {0.f,0.f,0.f,0.f};
    float bx[4] = {0.f,0.f,0.f,0.f}, by[4] = {0.f,0.f,0.f,0.f};

    #define PROC(EW, M, PX, PY)                                                 \
    for (int tt = 0; tt < (M); tt += 16) {                                      \
        _Pragma("unroll")                                                       \
        for (int j = 0; j < 16; ++j) {                                          \
            int t = tt + j;                                                     \
            int tc = (t < (M)) ? t : ((M) - 1);                                 \
            u32 es = (u32)__builtin_amdgcn_readlane((int)(EW), tc);             \
            float v = (t < (M)) ? __uint_as_float((es >> 17) << 16) : 0.0f;     \
            u32 col = es & 0x1FFFFu;                                            \
            const u16* rp = H8 + (size_t)col * 64;                              \
            u32 h = rp[lane];                                                   \
            f32x2 f = __builtin_amdgcn_cvt_pk_f32_fp8(h, false);                \
            PX[j & 3] = fmaf(v, f[0], PX[j & 3]);                               \
            PY[j & 3] = fmaf(v, f[1], PY[j & 3]);                               \
        }                                                                       \
    }

    PROC(ew0, m0, ax, ay)
    // rare long-row chunks (P(len>64) ~ 0 at Poisson(32))
    for (int t0 = 64; t0 < len0; t0 += 64) {
        int rem = len0 - t0;
        int m = (rem < 64) ? rem : 64;
        int tc = (lane < m) ? lane : (m - 1);
        u32 ew = edges[s0 + t0 + tc];
        PROC(ew, m, ax, ay)
    }
    PROC(ew1, m1, bx, by)
    for (int t0 = 64; t0 < len1; t0 += 64) {
        int rem = len1 - t0;
        int m = (rem < 64) ? rem : 64;
        int tc = (lane < m) ? lane : (m - 1);
        u32 ew = edges[e0 + t0 + tc];
        PROC(ew, m, bx, by)
    }
    #undef PROC

    float axs = (ax[0] + ax[1]) + (ax[2] + ax[3]);
    float ays = (ay[0] + ay[1]) + (ay[2] + ay[3]);
    float bxs = (bx[0] + bx[1]) + (bx[2] + bx[3]);
    float bys = (by[0] + by[1]) + (by[2] + by[3]);
    if (!isfinite(axs)) axs = 0.0f;
    if (!isfinite(ays)) ays = 0.0f;
    if (!isfinite(bxs)) bxs = 0.0f;
    if (!isfinite(bys)) bys = 0.0f;

    size_t o0 = (size_t)row0 * 64 + lane;
    size_t o1 = o0 + 64;
    if (WR == 2) {
        float w0 = w[0], w1 = w[1];
        float2 xv0 = ((const float2*)Xf)[o0];
        float2 xv1 = ((const float2*)Xf)[o1];
        f32x2 r0, r1;
        r0[0] = fmaf(w1, axs, w0 * xv0.x);
        r0[1] = fmaf(w1, ays, w0 * xv0.y);
        r1[0] = fmaf(w1, bxs, w0 * xv1.x);
        r1[1] = fmaf(w1, bys, w0 * xv1.y);
        __builtin_nontemporal_store(r0, &((f32x2*)out)[o0]);
        __builtin_nontemporal_store(r1, &((f32x2*)out)[o1]);
    } else {
        float cc = w[l + 1] / w[l];
        u32 xb0 = __builtin_nontemporal_load((const u32*)Xbf + o0);
        u32 xb1 = __builtin_nontemporal_load((const u32*)Xbf + o1);
        float z0x = fmaf(cc, axs, bf2f(xb0 & 0xFFFFu));
        float z0y = fmaf(cc, ays, bf2f(xb0 >> 16));
        float z1x = fmaf(cc, bxs, bf2f(xb1 & 0xFFFFu));
        float z1y = fmaf(cc, bys, bf2f(xb1 >> 16));
        u32 p0 = __builtin_amdgcn_cvt_pk_fp8_f32(z0x, z0y, 0, false);
        u32 p1 = __builtin_amdgcn_cvt_pk_fp8_f32(z1x, z1y, 0, false);
        __builtin_nontemporal_store((u16)p0, (u16*)Znew + o0);
        __builtin_nontemporal_store((u16)p1, (u16*)Znew + o1);
    }
}

extern "C" void kernel_launch(void* const* d_in, const int* in_sizes, int n_in,
                              void* d_out, int out_size, void* d_ws, size_t ws_size,
                              hipStream_t stream) {
    const int*   erow  = (const int*)d_in[0];
    const int*   ecol  = (const int*)d_in[1];
    const float* evals = (const float*)d_in[2];
    const float* X     = (const float*)d_in[3];
    const float* w     = (const float*)d_in[4];
    float* out = (float*)d_out;

    const size_t n = (size_t)N_NODES * D_FEAT;  // 12.8M elements

    // workspace layout (~90 MB)
    char* base = (char*)d_ws;
    u8*  Za      = (u8*)base;                   // fp8, n bytes (init: Zhat_10 = fp8(X))
    u8*  Zb      = (u8*)(base + n);             // fp8, n bytes
    u16* Xbf     = (u16*)(base + 2 * n);        // bf16, 2n bytes
    u64* packedA = (u64*)(base + 4 * n);        // 3.2M u64 = 25.6 MB, dead after binB
    int* row_ptr = (int*)(base + 6 * n);        // 100001 (padded 100352)
    int* bucket_base   = row_ptr + 100352;
    int* bucket_cursor = bucket_base + 1024;
    int* bcount        = bucket_cursor + 1024;
    u32* edges   = (u32*)(bcount + 1024);       // 3.2M u32 = 12.8 MB

    dim3 b256(256);

    // CSR build
    hipMemsetAsync(bcount, 0, NBUCKETS * sizeof(int), stream);
    gpr_bucket_hist<<<dim3(512), b256, 0, stream>>>(erow, bcount);
    gpr_bucket_scan<<<dim3(1), dim3(1024), 0, stream>>>(bcount, bucket_base, bucket_cursor, row_ptr);
    gpr_binA<<<dim3(NA_BLOCKS), b256, 0, stream>>>(erow, ecol, evals, bucket_cursor, packedA);
    gpr_binB<<<dim3(NBUCKETS), b256, 0, stream>>>(bucket_base, packedA, row_ptr, edges);

    // Xbf = bf16(X), Za = fp8(X) = Zhat_10
    gpr_init<<<dim3((unsigned)((n / 4 + 255) / 256)), b256, 0, stream>>>(X, Xbf, Za, (int)(n / 4));

    dim3 spmm_grid((N_NODES / 2 + 3) / 4);      // 12500 blocks, 2 rows/wave
    // hops k = 9..1: fp8 -> fp8
    const void* Zold = Za;
    for (int k = L_FILTERS - 1; k >= 1; --k) {
        void* Znew = (Zold == (void*)Za) ? (void*)Zb : (void*)Za;
        gpr_spmm<0><<<spmm_grid, b256, 0, stream>>>(row_ptr, edges, Zold, Xbf, X, w, k, Znew, nullptr);
        Zold = Znew;
    }
    // hop k = 0 (final): fp8 -> fp32 out = w0*X + w1 * A * Zhat_1
    gpr_spmm<2><<<spmm_grid, b256, 0, stream>>>(row_ptr, edges, Zold, Xbf, X, w, 0, nullptr, out);
}

// Round 10
// 911.361 us; speedup vs baseline: 1.5473x; 1.0294x over previous
//
#include <hip/hip_runtime.h>
#include <math.h>

#define N_NODES   100000
#define D_FEAT    128
#define N_EDGES   3200000
#define L_FILTERS 10

#define RPB_LOG   7
#define RPB       128
#define NBUCKETS  ((N_NODES + RPB - 1) >> RPB_LOG)     // 782
#define CHUNK     8192
#define NA_BLOCKS ((N_EDGES + CHUNK - 1) / CHUNK)      // 391

typedef unsigned char  u8;
typedef unsigned int   u32;
typedef unsigned short u16;
typedef unsigned long long u64;
typedef float f32x2 __attribute__((ext_vector_type(2)));

static __device__ __forceinline__ u16 f2bf(float f) {
    u32 u = __float_as_uint(f);
    u32 r = (u + 0x7FFFu + ((u >> 16) & 1u)) >> 16;   // RNE
    return (u16)r;
}
static __device__ __forceinline__ float bf2f(u32 b) {
    return __uint_as_float(b << 16);
}

// ---------------- init: Xbf = bf16(X), Xf8 = fp8(X)  (Xf8 doubles as Zhat_10 = X) -----
__global__ void gpr_init(const float* __restrict__ X,
                         u16* __restrict__ Xbf, u8* __restrict__ Xf8, int n4) {
    int i = blockIdx.x * blockDim.x + threadIdx.x;
    if (i >= n4) return;
    float4 v = ((const float4*)X)[i];
    ushort4 b;
    b.x = f2bf(v.x); b.y = f2bf(v.y); b.z = f2bf(v.z); b.w = f2bf(v.w);
    ((ushort4*)Xbf)[i] = b;
    u32 p01 = __builtin_amdgcn_cvt_pk_fp8_f32(v.x, v.y, 0, false) & 0xFFFFu;
    u32 p23 = __builtin_amdgcn_cvt_pk_fp8_f32(v.z, v.w, 0, false) & 0xFFFFu;
    ((u32*)Xf8)[i] = p01 | (p23 << 16);
}

// ---------------- bucket histogram (LDS-private, 1 global atomic per bucket/block) ----
__global__ __launch_bounds__(256) void gpr_bucket_hist(const int* __restrict__ rows,
                                                       int* __restrict__ bcount) {
    __shared__ int hist[NBUCKETS];
    int t = threadIdx.x;
    for (int i = t; i < NBUCKETS; i += 256) hist[i] = 0;
    __syncthreads();
    int stride = gridDim.x * 256;
    for (int e = blockIdx.x * 256 + t; e < N_EDGES; e += stride)
        atomicAdd(&hist[rows[e] >> RPB_LOG], 1);
    __syncthreads();
    for (int i = t; i < NBUCKETS; i += 256)
        if (hist[i]) atomicAdd(&bcount[i], hist[i]);
}

// ---------------- scan 782 bucket counts (single block) ----------------
__global__ __launch_bounds__(1024) void gpr_bucket_scan(const int* __restrict__ bcount,
                                                        int* __restrict__ bucket_base,
                                                        int* __restrict__ bucket_cursor,
                                                        int* __restrict__ row_ptr) {
    __shared__ int buf[1024];
    int t = threadIdx.x;
    int v = (t < NBUCKETS) ? bcount[t] : 0;
    buf[t] = v; __syncthreads();
    for (int off = 1; off < 1024; off <<= 1) {
        int x = (t >= off) ? buf[t - off] : 0;
        __syncthreads();
        buf[t] += x;
        __syncthreads();
    }
    if (t < NBUCKETS) {
        int ex = buf[t] - v;
        bucket_base[t] = ex;
        bucket_cursor[t] = ex;
    }
    if (t == 0) {
        bucket_base[NBUCKETS] = N_EDGES;
        row_ptr[N_NODES] = N_EDGES;
    }
}

// ---------------- phase A: coarse bin into buckets, coalesced writes ----------------
// pack: val15[34:49) | row17[17:34) | col17[0:17)
__global__ __launch_bounds__(256) void gpr_binA(const int* __restrict__ rows,
                                                const int* __restrict__ cols,
                                                const float* __restrict__ vals,
                                                int* __restrict__ bucket_cursor,
                                                u64* __restrict__ packedA) {
    __shared__ u64 stage[CHUNK];
    __shared__ int hist[NBUCKETS];
    __shared__ int lbase[NBUCKETS];
    __shared__ int lcur[NBUCKETS];
    __shared__ int goff[NBUCKETS];
    __shared__ int psum[256];
    int t = threadIdx.x;
    long long base = (long long)blockIdx.x * CHUNK;
    for (int i = t; i < NBUCKETS; i += 256) hist[i] = 0;
    __syncthreads();
    for (int j = 0; j < CHUNK / 256; ++j) {
        long long e = base + j * 256 + t;
        if (e < N_EDGES) atomicAdd(&hist[rows[e] >> RPB_LOG], 1);
    }
    __syncthreads();
    int s = 0, b0 = t * 4;
    #pragma unroll
    for (int j = 0; j < 4; ++j) { int b = b0 + j; if (b < NBUCKETS) s += hist[b]; }
    psum[t] = s; __syncthreads();
    for (int off = 1; off < 256; off <<= 1) {
        int x = (t >= off) ? psum[t - off] : 0;
        __syncthreads();
        psum[t] += x;
        __syncthreads();
    }
    int run = psum[t] - s;
    #pragma unroll
    for (int j = 0; j < 4; ++j) {
        int b = b0 + j;
        if (b < NBUCKETS) { lbase[b] = run; run += hist[b]; }
    }
    __syncthreads();
    for (int i = t; i < NBUCKETS; i += 256) {
        lcur[i] = lbase[i];
        int g = (hist[i]) ? atomicAdd(&bucket_cursor[i], hist[i]) : 0;
        goff[i] = g - lbase[i];
    }
    __syncthreads();
    for (int j = 0; j < CHUNK / 256; ++j) {
        long long e = base + j * 256 + t;
        if (e < N_EDGES) {
            int r = rows[e];
            u32 vb = (u32)f2bf(vals[e]);
            u64 p = ((u64)vb << 34) | ((u64)(u32)r << 17) | (u64)(u32)cols[e];
            int pos = atomicAdd(&lcur[r >> RPB_LOG], 1);
            stage[pos] = p;
        }
    }
    __syncthreads();
    long long rem = (long long)N_EDGES - base;
    int total = (rem < CHUNK) ? (int)rem : CHUNK;
    for (int idx = t; idx < total; idx += 256) {
        u64 p = stage[idx];
        int b = (int)((p >> 17) & 0x1FFFFu) >> RPB_LOG;
        packedA[goff[b] + idx] = p;
    }
}

// ---------------- phase B: per-bucket row histogram + scan + row_ptr + fine scatter ----
__global__ __launch_bounds__(256) void gpr_binB(const int* __restrict__ bucket_base,
                                                const u64* __restrict__ packedA,
                                                int* __restrict__ row_ptr,
                                                u32* __restrict__ edges) {
    __shared__ int cnt[RPB];
    __shared__ int sbuf[RPB];
    __shared__ int cur[RPB];
    int b = blockIdx.x;
    int t = threadIdx.x;
    int r0 = b << RPB_LOG;
    int r1 = r0 + RPB; if (r1 > N_NODES) r1 = N_NODES;
    int lo = bucket_base[b], hi = bucket_base[b + 1];
    if (t < RPB) cnt[t] = 0;
    __syncthreads();
    for (int e = lo + t; e < hi; e += 256) {
        int r = (int)((packedA[e] >> 17) & 0x1FFFFu);
        atomicAdd(&cnt[r - r0], 1);
    }
    __syncthreads();
    if (t < RPB) sbuf[t] = cnt[t];
    __syncthreads();
    for (int off = 1; off < RPB; off <<= 1) {
        int x = (t < RPB && t >= off) ? sbuf[t - off] : 0;
        __syncthreads();
        if (t < RPB) sbuf[t] += x;
        __syncthreads();
    }
    if (t < RPB) {
        int ex = sbuf[t] - cnt[t];
        cur[t] = ex;
        if (r0 + t < r1) row_ptr[r0 + t] = lo + ex;
    }
    __syncthreads();
    for (int e = lo + t; e < hi; e += 256) {
        u64 p = packedA[e];
        int r = (int)((p >> 17) & 0x1FFFFu);
        int pos = lo + atomicAdd(&cur[r - r0], 1);
        edges[pos] = (u32)(((p >> 34) << 17) | (p & 0x1FFFFu));
    }
}

// ---------------- Horner SpMM on normalized fp8 states ----------------
// Zhat_l = X + (w[l+1]/w[l]) * A * Zhat_{l+1}   (WR 0 = fp8 state out, 2 = f32 final)
// final:  out = w0*X + w1 * A * Zhat_1
//
// Structure: one wave per TWO consecutive rows, 2 feats/lane (round-7 form)
// + TWO-BATCH SOFTWARE PIPELINE: batch b+1's 8 gathers are issued BEFORE
// batch b is consumed, alternating two named 8-register banks (hA/hB).
// No register copies (a g->h move would force a vmcnt drain); batch
// boundaries are uniform scalar branches. Steady-state outstanding gathers
// ~8-12/wave vs round-7's ~3 (single batch drains to 0 while consuming).
// Live staged regs = 16 max -> VGPR ~40s, stays in the 8-waves/SIMD band.
// Tail edges clamp to the row's last edge (hot line) and contribute v = 0.

#define IS8(EW, TT, H)                                                          \
    { _Pragma("unroll")                                                         \
      for (int j = 0; j < 8; ++j) {                                             \
          u32 es = (u32)__builtin_amdgcn_readlane((int)(EW), (TT) + j);         \
          H[j] = *(const u16*)((const u8*)H8 + (size_t)((es & 0x1FFFFu) << 7) + lane2); \
      } }

#define CO8(EW, M, TT, H, PX, PY)                                               \
    { _Pragma("unroll")                                                         \
      for (int j = 0; j < 8; ++j) {                                             \
          int t = (TT) + j;                                                     \
          u32 es = (u32)__builtin_amdgcn_readlane((int)(EW), t);                \
          float v = (t < (M)) ? __uint_as_float((es >> 17) << 16) : 0.0f;       \
          f32x2 f = __builtin_amdgcn_cvt_pk_f32_fp8(H[j], false);               \
          PX[j & 3] = fmaf(v, f[0], PX[j & 3]);                                 \
          PY[j & 3] = fmaf(v, f[1], PY[j & 3]);                                 \
      } }

#define PIPE(EW, M, PX, PY)                                                     \
    {                                                                           \
        u32 hA[8], hB[8];                                                       \
        IS8(EW, 0, hA)                                                          \
        if ((M) > 8)  IS8(EW, 8, hB)                                            \
        CO8(EW, M, 0, hA, PX, PY)                                               \
        if ((M) > 16) IS8(EW, 16, hA)                                           \
        if ((M) > 8)  CO8(EW, M, 8, hB, PX, PY)                                 \
        if ((M) > 24) IS8(EW, 24, hB)                                           \
        if ((M) > 16) CO8(EW, M, 16, hA, PX, PY)                                \
        if ((M) > 32) IS8(EW, 32, hA)                                           \
        if ((M) > 24) CO8(EW, M, 24, hB, PX, PY)                                \
        if ((M) > 40) IS8(EW, 40, hB)                                           \
        if ((M) > 32) CO8(EW, M, 32, hA, PX, PY)                                \
        if ((M) > 48) IS8(EW, 48, hA)                                           \
        if ((M) > 40) CO8(EW, M, 40, hB, PX, PY)                                \
        if ((M) > 56) IS8(EW, 56, hB)                                           \
        if ((M) > 48) CO8(EW, M, 48, hA, PX, PY)                                \
        if ((M) > 56) CO8(EW, M, 56, hB, PX, PY)                                \
    }

template<int WR>
__global__ __launch_bounds__(256) void gpr_spmm(
    const int* __restrict__ row_ptr, const u32* __restrict__ edges,
    const void* __restrict__ Zold, const u16* __restrict__ Xbf,
    const float* __restrict__ Xf, const float* __restrict__ w, int l,
    void* __restrict__ Znew, float* __restrict__ out) {
    int pr = (int)(blockIdx.x * 4 + (threadIdx.x >> 6));
    pr = __builtin_amdgcn_readfirstlane(pr);
    if (pr >= N_NODES / 2) return;
    int row0 = pr * 2;
    int lane = threadIdx.x & 63;
    int lane2 = lane * 2;
    int s0 = __builtin_amdgcn_readfirstlane(row_ptr[row0]);
    int e0 = __builtin_amdgcn_readfirstlane(row_ptr[row0 + 1]);
    int e1 = __builtin_amdgcn_readfirstlane(row_ptr[row0 + 2]);
    int len0 = e0 - s0, len1 = e1 - e0;
    int m0 = (len0 < 64) ? len0 : 64;
    int m1 = (len1 < 64) ? len1 : 64;

    const u16* H8 = (const u16*)Zold;    // fp8 row-major: 2 fp8 feats per u16, 128 B/row

    // issue both rows' first edge-chunks up-front (independent loads)
    u32 ew0 = 0, ew1 = 0;
    if (m0 > 0) { int tc = (lane < m0) ? lane : (m0 - 1); ew0 = edges[s0 + tc]; }
    if (m1 > 0) { int tc = (lane < m1) ? lane : (m1 - 1); ew1 = edges[e0 + tc]; }

    float ax[4] = {0.f,0.f,0.f,0.f}, ay[4] = {0.f,0.f,0.f,0.f};
    float bx[4] = {0.f,0.f,0.f,0.f}, by[4] = {0.f,0.f,0.f,0.f};

    PIPE(ew0, m0, ax, ay)
    // rare long-row chunks (P(len>64) ~ 0 at Poisson(32))
    for (int t0 = 64; t0 < len0; t0 += 64) {
        int rem = len0 - t0;
        int m = (rem < 64) ? rem : 64;
        int tc = (lane < m) ? lane : (m - 1);
        u32 ew = edges[s0 + t0 + tc];
        PIPE(ew, m, ax, ay)
    }
    PIPE(ew1, m1, bx, by)
    for (int t0 = 64; t0 < len1; t0 += 64) {
        int rem = len1 - t0;
        int m = (rem < 64) ? rem : 64;
        int tc = (lane < m) ? lane : (m - 1);
        u32 ew = edges[e0 + t0 + tc];
        PIPE(ew, m, bx, by)
    }

    float axs = (ax[0] + ax[1]) + (ax[2] + ax[3]);
    float ays = (ay[0] + ay[1]) + (ay[2] + ay[3]);
    float bxs = (bx[0] + bx[1]) + (bx[2] + bx[3]);
    float bys = (by[0] + by[1]) + (by[2] + by[3]);
    if (!isfinite(axs)) axs = 0.0f;
    if (!isfinite(ays)) ays = 0.0f;
    if (!isfinite(bxs)) bxs = 0.0f;
    if (!isfinite(bys)) bys = 0.0f;

    size_t o0 = (size_t)row0 * 64 + lane;
    size_t o1 = o0 + 64;
    if (WR == 2) {
        float w0 = w[0], w1 = w[1];
        float2 xv0 = ((const float2*)Xf)[o0];
        float2 xv1 = ((const float2*)Xf)[o1];
        f32x2 r0, r1;
        r0[0] = fmaf(w1, axs, w0 * xv0.x);
        r0[1] = fmaf(w1, ays, w0 * xv0.y);
        r1[0] = fmaf(w1, bxs, w0 * xv1.x);
        r1[1] = fmaf(w1, bys, w0 * xv1.y);
        __builtin_nontemporal_store(r0, &((f32x2*)out)[o0]);
        __builtin_nontemporal_store(r1, &((f32x2*)out)[o1]);
    } else {
        float cc = w[l + 1] / w[l];
        u32 xb0 = __builtin_nontemporal_load((const u32*)Xbf + o0);
        u32 xb1 = __builtin_nontemporal_load((const u32*)Xbf + o1);
        float z0x = fmaf(cc, axs, bf2f(xb0 & 0xFFFFu));
        float z0y = fmaf(cc, ays, bf2f(xb0 >> 16));
        float z1x = fmaf(cc, bxs, bf2f(xb1 & 0xFFFFu));
        float z1y = fmaf(cc, bys, bf2f(xb1 >> 16));
        u32 p0 = __builtin_amdgcn_cvt_pk_fp8_f32(z0x, z0y, 0, false);
        u32 p1 = __builtin_amdgcn_cvt_pk_fp8_f32(z1x, z1y, 0, false);
        __builtin_nontemporal_store((u16)p0, (u16*)Znew + o0);
        __builtin_nontemporal_store((u16)p1, (u16*)Znew + o1);
    }
}

extern "C" void kernel_launch(void* const* d_in, const int* in_sizes, int n_in,
                              void* d_out, int out_size, void* d_ws, size_t ws_size,
                              hipStream_t stream) {
    const int*   erow  = (const int*)d_in[0];
    const int*   ecol  = (const int*)d_in[1];
    const float* evals = (const float*)d_in[2];
    const float* X     = (const float*)d_in[3];
    const float* w     = (const float*)d_in[4];
    float* out = (float*)d_out;

    const size_t n = (size_t)N_NODES * D_FEAT;  // 12.8M elements

    // workspace layout (~90 MB)
    char* base = (char*)d_ws;
    u8*  Za      = (u8*)base;                   // fp8, n bytes (init: Zhat_10 = fp8(X))
    u8*  Zb      = (u8*)(base + n);             // fp8, n bytes
    u16* Xbf     = (u16*)(base + 2 * n);        // bf16, 2n bytes
    u64* packedA = (u64*)(base + 4 * n);        // 3.2M u64 = 25.6 MB, dead after binB
    int* row_ptr = (int*)(base + 6 * n);        // 100001 (padded 100352)
    int* bucket_base   = row_ptr + 100352;
    int* bucket_cursor = bucket_base + 1024;
    int* bcount        = bucket_cursor + 1024;
    u32* edges   = (u32*)(bcount + 1024);       // 3.2M u32 = 12.8 MB

    dim3 b256(256);

    // CSR build
    hipMemsetAsync(bcount, 0, NBUCKETS * sizeof(int), stream);
    gpr_bucket_hist<<<dim3(512), b256, 0, stream>>>(erow, bcount);
    gpr_bucket_scan<<<dim3(1), dim3(1024), 0, stream>>>(bcount, bucket_base, bucket_cursor, row_ptr);
    gpr_binA<<<dim3(NA_BLOCKS), b256, 0, stream>>>(erow, ecol, evals, bucket_cursor, packedA);
    gpr_binB<<<dim3(NBUCKETS), b256, 0, stream>>>(bucket_base, packedA, row_ptr, edges);

    // Xbf = bf16(X), Za = fp8(X) = Zhat_10
    gpr_init<<<dim3((unsigned)((n / 4 + 255) / 256)), b256, 0, stream>>>(X, Xbf, Za, (int)(n / 4));

    dim3 spmm_grid((N_NODES / 2 + 3) / 4);      // 12500 blocks, 2 rows/wave
    // hops k = 9..1: fp8 -> fp8
    const void* Zold = Za;
    for (int k = L_FILTERS - 1; k >= 1; --k) {
        void* Znew = (Zold == (void*)Za) ? (void*)Zb : (void*)Za;
        gpr_spmm<0><<<spmm_grid, b256, 0, stream>>>(row_ptr, edges, Zold, Xbf, X, w, k, Znew, nullptr);
        Zold = Znew;
    }
    // hop k = 0 (final): fp8 -> fp32 out = w0*X + w1 * A * Zhat_1
    gpr_spmm<2><<<spmm_grid, b256, 0, stream>>>(row_ptr, edges, Zold, Xbf, X, w, 0, nullptr, out);
}

// Round 11
// 900.901 us; speedup vs baseline: 1.5653x; 1.0116x over previous
//
#include <hip/hip_runtime.h>
#include <math.h>

#define N_NODES   100000
#define D_FEAT    128
#define N_EDGES   3200000
#define L_FILTERS 10

#define RPB_LOG   7
#define RPB       128
#define NBUCKETS  ((N_NODES + RPB - 1) >> RPB_LOG)     // 782
#define CHUNK     8192
#define NA_BLOCKS ((N_EDGES + CHUNK - 1) / CHUNK)      // 391

typedef unsigned char  u8;
typedef unsigned int   u32;
typedef unsigned short u16;
typedef unsigned long long u64;
typedef float f32x2 __attribute__((ext_vector_type(2)));

static __device__ __forceinline__ u16 f2bf(float f) {
    u32 u = __float_as_uint(f);
    u32 r = (u + 0x7FFFu + ((u >> 16) & 1u)) >> 16;   // RNE
    return (u16)r;
}
static __device__ __forceinline__ float bf2f(u32 b) {
    return __uint_as_float(b << 16);
}

// ---------------- init: Xbf = bf16(X), Xf8 = fp8(X)  (Xf8 doubles as Zhat_10 = X) -----
__global__ void gpr_init(const float* __restrict__ X,
                         u16* __restrict__ Xbf, u8* __restrict__ Xf8, int n4) {
    int i = blockIdx.x * blockDim.x + threadIdx.x;
    if (i >= n4) return;
    float4 v = ((const float4*)X)[i];
    ushort4 b;
    b.x = f2bf(v.x); b.y = f2bf(v.y); b.z = f2bf(v.z); b.w = f2bf(v.w);
    ((ushort4*)Xbf)[i] = b;
    u32 p01 = __builtin_amdgcn_cvt_pk_fp8_f32(v.x, v.y, 0, false) & 0xFFFFu;
    u32 p23 = __builtin_amdgcn_cvt_pk_fp8_f32(v.z, v.w, 0, false) & 0xFFFFu;
    ((u32*)Xf8)[i] = p01 | (p23 << 16);
}

// ---------------- bucket histogram (LDS-private, 1 global atomic per bucket/block) ----
__global__ __launch_bounds__(256) void gpr_bucket_hist(const int* __restrict__ rows,
                                                       int* __restrict__ bcount) {
    __shared__ int hist[NBUCKETS];
    int t = threadIdx.x;
    for (int i = t; i < NBUCKETS; i += 256) hist[i] = 0;
    __syncthreads();
    int stride = gridDim.x * 256;
    for (int e = blockIdx.x * 256 + t; e < N_EDGES; e += stride)
        atomicAdd(&hist[rows[e] >> RPB_LOG], 1);
    __syncthreads();
    for (int i = t; i < NBUCKETS; i += 256)
        if (hist[i]) atomicAdd(&bcount[i], hist[i]);
}

// ---------------- scan 782 bucket counts (single block) ----------------
__global__ __launch_bounds__(1024) void gpr_bucket_scan(const int* __restrict__ bcount,
                                                        int* __restrict__ bucket_base,
                                                        int* __restrict__ bucket_cursor,
                                                        int* __restrict__ row_ptr) {
    __shared__ int buf[1024];
    int t = threadIdx.x;
    int v = (t < NBUCKETS) ? bcount[t] : 0;
    buf[t] = v; __syncthreads();
    for (int off = 1; off < 1024; off <<= 1) {
        int x = (t >= off) ? buf[t - off] : 0;
        __syncthreads();
        buf[t] += x;
        __syncthreads();
    }
    if (t < NBUCKETS) {
        int ex = buf[t] - v;
        bucket_base[t] = ex;
        bucket_cursor[t] = ex;
    }
    if (t == 0) {
        bucket_base[NBUCKETS] = N_EDGES;
        row_ptr[N_NODES] = N_EDGES;
    }
}

// ---------------- phase A: coarse bin into buckets, coalesced writes ----------------
// pack: val16[34:50) | row17[17:34) | col17[0:17)
__global__ __launch_bounds__(256) void gpr_binA(const int* __restrict__ rows,
                                                const int* __restrict__ cols,
                                                const float* __restrict__ vals,
                                                int* __restrict__ bucket_cursor,
                                                u64* __restrict__ packedA) {
    __shared__ u64 stage[CHUNK];
    __shared__ int hist[NBUCKETS];
    __shared__ int lbase[NBUCKETS];
    __shared__ int lcur[NBUCKETS];
    __shared__ int goff[NBUCKETS];
    __shared__ int psum[256];
    int t = threadIdx.x;
    long long base = (long long)blockIdx.x * CHUNK;
    for (int i = t; i < NBUCKETS; i += 256) hist[i] = 0;
    __syncthreads();
    for (int j = 0; j < CHUNK / 256; ++j) {
        long long e = base + j * 256 + t;
        if (e < N_EDGES) atomicAdd(&hist[rows[e] >> RPB_LOG], 1);
    }
    __syncthreads();
    int s = 0, b0 = t * 4;
    #pragma unroll
    for (int j = 0; j < 4; ++j) { int b = b0 + j; if (b < NBUCKETS) s += hist[b]; }
    psum[t] = s; __syncthreads();
    for (int off = 1; off < 256; off <<= 1) {
        int x = (t >= off) ? psum[t - off] : 0;
        __syncthreads();
        psum[t] += x;
        __syncthreads();
    }
    int run = psum[t] - s;
    #pragma unroll
    for (int j = 0; j < 4; ++j) {
        int b = b0 + j;
        if (b < NBUCKETS) { lbase[b] = run; run += hist[b]; }
    }
    __syncthreads();
    for (int i = t; i < NBUCKETS; i += 256) {
        lcur[i] = lbase[i];
        int g = (hist[i]) ? atomicAdd(&bucket_cursor[i], hist[i]) : 0;
        goff[i] = g - lbase[i];
    }
    __syncthreads();
    for (int j = 0; j < CHUNK / 256; ++j) {
        long long e = base + j * 256 + t;
        if (e < N_EDGES) {
            int r = rows[e];
            u32 vb = (u32)f2bf(vals[e]);
            u64 p = ((u64)vb << 34) | ((u64)(u32)r << 17) | (u64)(u32)cols[e];
            int pos = atomicAdd(&lcur[r >> RPB_LOG], 1);
            stage[pos] = p;
        }
    }
    __syncthreads();
    long long rem = (long long)N_EDGES - base;
    int total = (rem < CHUNK) ? (int)rem : CHUNK;
    for (int idx = t; idx < total; idx += 256) {
        u64 p = stage[idx];
        int b = (int)((p >> 17) & 0x1FFFFu) >> RPB_LOG;
        packedA[goff[b] + idx] = p;
    }
}

// ---------------- phase B: per-bucket row hist + scan + row_ptr + IN-PLACE edge emit --
// Transforms packedA (bucket-grouped) into row-sorted u64 edge words IN PLACE:
//   hi32 = f32 bits of bf16(val)  (ready for fmaf, zero extraction SALU)
//   lo32 = col << 7               (ready byte offset into a 128-B fp8 state row)
// Each bucket (<= 8192 entries, mean 4096 + 64 sigma bound) is staged in LDS
// before any write, so in-place is race-free (blocks own disjoint ranges).
__global__ __launch_bounds__(256) void gpr_binB(const int* __restrict__ bucket_base,
                                                u64* __restrict__ packedA,
                                                int* __restrict__ row_ptr) {
    __shared__ u64 stage[CHUNK];
    __shared__ int cnt[RPB];
    __shared__ int sbuf[RPB];
    __shared__ int cur[RPB];
    int b = blockIdx.x;
    int t = threadIdx.x;
    int r0 = b << RPB_LOG;
    int r1 = r0 + RPB; if (r1 > N_NODES) r1 = N_NODES;
    int lo = bucket_base[b], hi = bucket_base[b + 1];
    int num = hi - lo;
    if (t < RPB) cnt[t] = 0;
    __syncthreads();
    for (int i = t; i < num; i += 256) {
        u64 p = packedA[lo + i];
        stage[i] = p;
        atomicAdd(&cnt[((int)(p >> 17) & 0x1FFFF) - r0], 1);
    }
    __syncthreads();
    if (t < RPB) sbuf[t] = cnt[t];
    __syncthreads();
    for (int off = 1; off < RPB; off <<= 1) {
        int x = (t < RPB && t >= off) ? sbuf[t - off] : 0;
        __syncthreads();
        if (t < RPB) sbuf[t] += x;
        __syncthreads();
    }
    if (t < RPB) {
        int ex = sbuf[t] - cnt[t];
        cur[t] = ex;
        if (r0 + t < r1) row_ptr[r0 + t] = lo + ex;
    }
    __syncthreads();
    for (int i = t; i < num; i += 256) {
        u64 p = stage[i];
        int r = (int)((p >> 17) & 0x1FFFFu);
        int pos = lo + atomicAdd(&cur[r - r0], 1);
        u32 vb  = (u32)(p >> 34);                 // bf16 word
        u32 col = (u32)(p & 0x1FFFFu);
        packedA[pos] = ((u64)(vb << 16) << 32) | (u64)(col << 7);
    }
}

// ---------------- Horner SpMM on normalized fp8 states ----------------
// Zhat_l = X + (w[l+1]/w[l]) * A * Zhat_{l+1}   (WR 0 = fp8 state out, 2 = f32 final)
// final:  out = w0*X + w1 * A * Zhat_1
//
// Round-7 wave structure (2 rows/wave, 2 feats/lane, consume-as-you-go) with the
// per-edge SCALAR work stripped (round-10 lesson: the CU's single scalar unit,
// shared by 4 SIMDs, was the bottleneck at ~10 SALU/edge = ~52 us/CU/hop):
//  - u64 edge words: hi = f32 value bits (no extract), lo = col<<7 (ready offset)
//    -> extraction = 2 v_readlane, 0 SALU
//  - clamp-free full 8-edge batches (m & ~7) + at most one clamped tail batch
//  Remaining per edge: 2 readlane + cvt + 2 fma (VALU), s_add64 (2 SALU), 1 VMEM.

#define FULL8(EWLO, EWHI, TT, PX, PY)                                           \
    { _Pragma("unroll")                                                         \
      for (int j = 0; j < 8; ++j) {                                             \
          int t = (TT) + j;                                                     \
          u32 off = (u32)__builtin_amdgcn_readlane((int)(EWLO), t);             \
          u32 vh  = (u32)__builtin_amdgcn_readlane((int)(EWHI), t);             \
          float v = __uint_as_float(vh);                                        \
          u32 h = *(const u16*)(H8 + off + lane2);                              \
          f32x2 f = __builtin_amdgcn_cvt_pk_f32_fp8(h, false);                  \
          PX[j & 3] = fmaf(v, f[0], PX[j & 3]);                                 \
          PY[j & 3] = fmaf(v, f[1], PY[j & 3]);                                 \
      } }

#define TAIL8(EWLO, EWHI, M, TT, PX, PY)                                        \
    { _Pragma("unroll")                                                         \
      for (int j = 0; j < 8; ++j) {                                             \
          int t = (TT) + j;                                                     \
          int tc = (t < (M)) ? t : ((M) - 1);                                   \
          u32 off = (u32)__builtin_amdgcn_readlane((int)(EWLO), tc);            \
          u32 vh  = (u32)__builtin_amdgcn_readlane((int)(EWHI), tc);            \
          float v = (t < (M)) ? __uint_as_float(vh) : 0.0f;                     \
          u32 h = *(const u16*)(H8 + off + lane2);                              \
          f32x2 f = __builtin_amdgcn_cvt_pk_f32_fp8(h, false);                  \
          PX[j & 3] = fmaf(v, f[0], PX[j & 3]);                                 \
          PY[j & 3] = fmaf(v, f[1], PY[j & 3]);                                 \
      } }

#define PROC(EWLO, EWHI, M, PX, PY)                                             \
    {                                                                           \
        int nfull = (M) & ~7;                                                   \
        for (int tt = 0; tt < nfull; tt += 8) FULL8(EWLO, EWHI, tt, PX, PY)     \
        if (nfull < (M)) TAIL8(EWLO, EWHI, M, nfull, PX, PY)                    \
    }

template<int WR>
__global__ __launch_bounds__(256) void gpr_spmm(
    const int* __restrict__ row_ptr, const u64* __restrict__ edges,
    const void* __restrict__ Zold, const u16* __restrict__ Xbf,
    const float* __restrict__ Xf, const float* __restrict__ w, int l,
    void* __restrict__ Znew, float* __restrict__ out) {
    int pr = (int)(blockIdx.x * 4 + (threadIdx.x >> 6));
    pr = __builtin_amdgcn_readfirstlane(pr);
    if (pr >= N_NODES / 2) return;
    int row0 = pr * 2;
    int lane = threadIdx.x & 63;
    int lane2 = lane * 2;
    int s0 = __builtin_amdgcn_readfirstlane(row_ptr[row0]);
    int e0 = __builtin_amdgcn_readfirstlane(row_ptr[row0 + 1]);
    int e1 = __builtin_amdgcn_readfirstlane(row_ptr[row0 + 2]);
    int len0 = e0 - s0, len1 = e1 - e0;
    int m0 = (len0 < 64) ? len0 : 64;
    int m1 = (len1 < 64) ? len1 : 64;

    const u8* H8 = (const u8*)Zold;      // fp8 row-major: 128 B per node row

    // issue both rows' first edge-chunks up-front (independent 512-B loads)
    u32 ew0lo = 0, ew0hi = 0, ew1lo = 0, ew1hi = 0;
    if (m0 > 0) {
        int tc = (lane < m0) ? lane : (m0 - 1);
        u64 ew = edges[s0 + tc];
        ew0lo = (u32)ew; ew0hi = (u32)(ew >> 32);
    }
    if (m1 > 0) {
        int tc = (lane < m1) ? lane : (m1 - 1);
        u64 ew = edges[e0 + tc];
        ew1lo = (u32)ew; ew1hi = (u32)(ew >> 32);
    }

    float ax[4] = {0.f,0.f,0.f,0.f}, ay[4] = {0.f,0.f,0.f,0.f};
    float bx[4] = {0.f,0.f,0.f,0.f}, by[4] = {0.f,0.f,0.f,0.f};

    PROC(ew0lo, ew0hi, m0, ax, ay)
    // rare long-row chunks (P(len>64) ~ 0 at Poisson(32))
    for (int t0 = 64; t0 < len0; t0 += 64) {
        int rem = len0 - t0;
        int m = (rem < 64) ? rem : 64;
        int tc = (lane < m) ? lane : (m - 1);
        u64 ew = edges[s0 + t0 + tc];
        u32 elo = (u32)ew, ehi = (u32)(ew >> 32);
        PROC(elo, ehi, m, ax, ay)
    }
    PROC(ew1lo, ew1hi, m1, bx, by)
    for (int t0 = 64; t0 < len1; t0 += 64) {
        int rem = len1 - t0;
        int m = (rem < 64) ? rem : 64;
        int tc = (lane < m) ? lane : (m - 1);
        u64 ew = edges[e0 + t0 + tc];
        u32 elo = (u32)ew, ehi = (u32)(ew >> 32);
        PROC(elo, ehi, m, bx, by)
    }

    float axs = (ax[0] + ax[1]) + (ax[2] + ax[3]);
    float ays = (ay[0] + ay[1]) + (ay[2] + ay[3]);
    float bxs = (bx[0] + bx[1]) + (bx[2] + bx[3]);
    float bys = (by[0] + by[1]) + (by[2] + by[3]);
    if (!isfinite(axs)) axs = 0.0f;
    if (!isfinite(ays)) ays = 0.0f;
    if (!isfinite(bxs)) bxs = 0.0f;
    if (!isfinite(bys)) bys = 0.0f;

    size_t o0 = (size_t)row0 * 64 + lane;
    size_t o1 = o0 + 64;
    if (WR == 2) {
        float w0 = w[0], w1 = w[1];
        float2 xv0 = ((const float2*)Xf)[o0];
        float2 xv1 = ((const float2*)Xf)[o1];
        f32x2 r0, r1;
        r0[0] = fmaf(w1, axs, w0 * xv0.x);
        r0[1] = fmaf(w1, ays, w0 * xv0.y);
        r1[0] = fmaf(w1, bxs, w0 * xv1.x);
        r1[1] = fmaf(w1, bys, w0 * xv1.y);
        __builtin_nontemporal_store(r0, &((f32x2*)out)[o0]);
        __builtin_nontemporal_store(r1, &((f32x2*)out)[o1]);
    } else {
        float cc = w[l + 1] / w[l];
        u32 xb0 = __builtin_nontemporal_load((const u32*)Xbf + o0);
        u32 xb1 = __builtin_nontemporal_load((const u32*)Xbf + o1);
        float z0x = fmaf(cc, axs, bf2f(xb0 & 0xFFFFu));
        float z0y = fmaf(cc, ays, bf2f(xb0 >> 16));
        float z1x = fmaf(cc, bxs, bf2f(xb1 & 0xFFFFu));
        float z1y = fmaf(cc, bys, bf2f(xb1 >> 16));
        u32 p0 = __builtin_amdgcn_cvt_pk_fp8_f32(z0x, z0y, 0, false);
        u32 p1 = __builtin_amdgcn_cvt_pk_fp8_f32(z1x, z1y, 0, false);
        __builtin_nontemporal_store((u16)p0, (u16*)Znew + o0);
        __builtin_nontemporal_store((u16)p1, (u16*)Znew + o1);
    }
}

extern "C" void kernel_launch(void* const* d_in, const int* in_sizes, int n_in,
                              void* d_out, int out_size, void* d_ws, size_t ws_size,
                              hipStream_t stream) {
    const int*   erow  = (const int*)d_in[0];
    const int*   ecol  = (const int*)d_in[1];
    const float* evals = (const float*)d_in[2];
    const float* X     = (const float*)d_in[3];
    const float* w     = (const float*)d_in[4];
    float* out = (float*)d_out;

    const size_t n = (size_t)N_NODES * D_FEAT;  // 12.8M elements

    // workspace layout (~77 MB): u64 edges live IN the packedA region (in-place)
    char* base = (char*)d_ws;
    u8*  Za      = (u8*)base;                   // fp8, n bytes (init: Zhat_10 = fp8(X))
    u8*  Zb      = (u8*)(base + n);             // fp8, n bytes
    u16* Xbf     = (u16*)(base + 2 * n);        // bf16, 2n bytes
    u64* packedA = (u64*)(base + 4 * n);        // 3.2M u64 = 25.6 MB -> becomes edges
    int* row_ptr = (int*)(base + 6 * n);        // 100001 (padded 100352)
    int* bucket_base   = row_ptr + 100352;
    int* bucket_cursor = bucket_base + 1024;
    int* bcount        = bucket_cursor + 1024;

    dim3 b256(256);

    // CSR build
    hipMemsetAsync(bcount, 0, NBUCKETS * sizeof(int), stream);
    gpr_bucket_hist<<<dim3(512), b256, 0, stream>>>(erow, bcount);
    gpr_bucket_scan<<<dim3(1), dim3(1024), 0, stream>>>(bcount, bucket_base, bucket_cursor, row_ptr);
    gpr_binA<<<dim3(NA_BLOCKS), b256, 0, stream>>>(erow, ecol, evals, bucket_cursor, packedA);
    gpr_binB<<<dim3(NBUCKETS), b256, 0, stream>>>(bucket_base, packedA, row_ptr);

    // Xbf = bf16(X), Za = fp8(X) = Zhat_10
    gpr_init<<<dim3((unsigned)((n / 4 + 255) / 256)), b256, 0, stream>>>(X, Xbf, Za, (int)(n / 4));

    dim3 spmm_grid((N_NODES / 2 + 3) / 4);      // 12500 blocks, 2 rows/wave
    // hops k = 9..1: fp8 -> fp8
    const void* Zold = Za;
    for (int k = L_FILTERS - 1; k >= 1; --k) {
        void* Znew = (Zold == (void*)Za) ? (void*)Zb : (void*)Za;
        gpr_spmm<0><<<spmm_grid, b256, 0, stream>>>(row_ptr, packedA, Zold, Xbf, X, w, k, Znew, nullptr);
        Zold = Znew;
    }
    // hop k = 0 (final): fp8 -> fp32 out = w0*X + w1 * A * Zhat_1
    gpr_spmm<2><<<spmm_grid, b256, 0, stream>>>(row_ptr, packedA, Zold, Xbf, X, w, 0, nullptr, out);
}

// Round 12
// 863.692 us; speedup vs baseline: 1.6327x; 1.0431x over previous
//
#include <hip/hip_runtime.h>
#include <math.h>

#define N_NODES   100000
#define D_FEAT    128
#define N_EDGES   3200000
#define L_FILTERS 10

#define RPB_LOG   7
#define RPB       128
#define NBUCKETS  ((N_NODES + RPB - 1) >> RPB_LOG)     // 782
#define CHUNK     8192
#define NA_BLOCKS ((N_EDGES + CHUNK - 1) / CHUNK)      // 391

typedef unsigned char  u8;
typedef unsigned int   u32;
typedef unsigned short u16;
typedef unsigned long long u64;
typedef float f32x2 __attribute__((ext_vector_type(2)));

static __device__ __forceinline__ u16 f2bf(float f) {
    u32 u = __float_as_uint(f);
    u32 r = (u + 0x7FFFu + ((u >> 16) & 1u)) >> 16;   // RNE
    return (u16)r;
}
static __device__ __forceinline__ float bf2f(u32 b) {
    return __uint_as_float(b << 16);
}

// ---------------- init: Xbf = bf16(X), Xf8 = fp8(X)  (Xf8 doubles as Zhat_10 = X) -----
__global__ void gpr_init(const float* __restrict__ X,
                         u16* __restrict__ Xbf, u8* __restrict__ Xf8, int n4) {
    int i = blockIdx.x * blockDim.x + threadIdx.x;
    if (i >= n4) return;
    float4 v = ((const float4*)X)[i];
    ushort4 b;
    b.x = f2bf(v.x); b.y = f2bf(v.y); b.z = f2bf(v.z); b.w = f2bf(v.w);
    ((ushort4*)Xbf)[i] = b;
    u32 p01 = __builtin_amdgcn_cvt_pk_fp8_f32(v.x, v.y, 0, false) & 0xFFFFu;
    u32 p23 = __builtin_amdgcn_cvt_pk_fp8_f32(v.z, v.w, 0, false) & 0xFFFFu;
    ((u32*)Xf8)[i] = p01 | (p23 << 16);
}

// ---------------- bucket histogram (LDS-private, 1 global atomic per bucket/block) ----
__global__ __launch_bounds__(256) void gpr_bucket_hist(const int* __restrict__ rows,
                                                       int* __restrict__ bcount) {
    __shared__ int hist[NBUCKETS];
    int t = threadIdx.x;
    for (int i = t; i < NBUCKETS; i += 256) hist[i] = 0;
    __syncthreads();
    int stride = gridDim.x * 256;
    for (int e = blockIdx.x * 256 + t; e < N_EDGES; e += stride)
        atomicAdd(&hist[rows[e] >> RPB_LOG], 1);
    __syncthreads();
    for (int i = t; i < NBUCKETS; i += 256)
        if (hist[i]) atomicAdd(&bcount[i], hist[i]);
}

// ---------------- scan 782 bucket counts (single block) ----------------
__global__ __launch_bounds__(1024) void gpr_bucket_scan(const int* __restrict__ bcount,
                                                        int* __restrict__ bucket_base,
                                                        int* __restrict__ bucket_cursor,
                                                        int* __restrict__ row_ptr) {
    __shared__ int buf[1024];
    int t = threadIdx.x;
    int v = (t < NBUCKETS) ? bcount[t] : 0;
    buf[t] = v; __syncthreads();
    for (int off = 1; off < 1024; off <<= 1) {
        int x = (t >= off) ? buf[t - off] : 0;
        __syncthreads();
        buf[t] += x;
        __syncthreads();
    }
    if (t < NBUCKETS) {
        int ex = buf[t] - v;
        bucket_base[t] = ex;
        bucket_cursor[t] = ex;
    }
    if (t == 0) {
        bucket_base[NBUCKETS] = N_EDGES;
        row_ptr[N_NODES] = N_EDGES;
    }
}

// ---------------- phase A: coarse bin into buckets, coalesced writes ----------------
// pack: val15[34:49) | row17[17:34) | col17[0:17)
__global__ __launch_bounds__(256) void gpr_binA(const int* __restrict__ rows,
                                                const int* __restrict__ cols,
                                                const float* __restrict__ vals,
                                                int* __restrict__ bucket_cursor,
                                                u64* __restrict__ packedA) {
    __shared__ u64 stage[CHUNK];
    __shared__ int hist[NBUCKETS];
    __shared__ int lbase[NBUCKETS];
    __shared__ int lcur[NBUCKETS];
    __shared__ int goff[NBUCKETS];
    __shared__ int psum[256];
    int t = threadIdx.x;
    long long base = (long long)blockIdx.x * CHUNK;
    for (int i = t; i < NBUCKETS; i += 256) hist[i] = 0;
    __syncthreads();
    for (int j = 0; j < CHUNK / 256; ++j) {
        long long e = base + j * 256 + t;
        if (e < N_EDGES) atomicAdd(&hist[rows[e] >> RPB_LOG], 1);
    }
    __syncthreads();
    int s = 0, b0 = t * 4;
    #pragma unroll
    for (int j = 0; j < 4; ++j) { int b = b0 + j; if (b < NBUCKETS) s += hist[b]; }
    psum[t] = s; __syncthreads();
    for (int off = 1; off < 256; off <<= 1) {
        int x = (t >= off) ? psum[t - off] : 0;
        __syncthreads();
        psum[t] += x;
        __syncthreads();
    }
    int run = psum[t] - s;
    #pragma unroll
    for (int j = 0; j < 4; ++j) {
        int b = b0 + j;
        if (b < NBUCKETS) { lbase[b] = run; run += hist[b]; }
    }
    __syncthreads();
    for (int i = t; i < NBUCKETS; i += 256) {
        lcur[i] = lbase[i];
        int g = (hist[i]) ? atomicAdd(&bucket_cursor[i], hist[i]) : 0;
        goff[i] = g - lbase[i];
    }
    __syncthreads();
    for (int j = 0; j < CHUNK / 256; ++j) {
        long long e = base + j * 256 + t;
        if (e < N_EDGES) {
            int r = rows[e];
            u32 vb = (u32)f2bf(vals[e]);
            u64 p = ((u64)vb << 34) | ((u64)(u32)r << 17) | (u64)(u32)cols[e];
            int pos = atomicAdd(&lcur[r >> RPB_LOG], 1);
            stage[pos] = p;
        }
    }
    __syncthreads();
    long long rem = (long long)N_EDGES - base;
    int total = (rem < CHUNK) ? (int)rem : CHUNK;
    for (int idx = t; idx < total; idx += 256) {
        u64 p = stage[idx];
        int b = (int)((p >> 17) & 0x1FFFFu) >> RPB_LOG;
        packedA[goff[b] + idx] = p;
    }
}

// ---------------- phase B: per-bucket row histogram + scan + row_ptr + fine scatter ----
__global__ __launch_bounds__(256) void gpr_binB(const int* __restrict__ bucket_base,
                                                const u64* __restrict__ packedA,
                                                int* __restrict__ row_ptr,
                                                u32* __restrict__ edges) {
    __shared__ int cnt[RPB];
    __shared__ int sbuf[RPB];
    __shared__ int cur[RPB];
    int b = blockIdx.x;
    int t = threadIdx.x;
    int r0 = b << RPB_LOG;
    int r1 = r0 + RPB; if (r1 > N_NODES) r1 = N_NODES;
    int lo = bucket_base[b], hi = bucket_base[b + 1];
    if (t < RPB) cnt[t] = 0;
    __syncthreads();
    for (int e = lo + t; e < hi; e += 256) {
        int r = (int)((packedA[e] >> 17) & 0x1FFFFu);
        atomicAdd(&cnt[r - r0], 1);
    }
    __syncthreads();
    if (t < RPB) sbuf[t] = cnt[t];
    __syncthreads();
    for (int off = 1; off < RPB; off <<= 1) {
        int x = (t < RPB && t >= off) ? sbuf[t - off] : 0;
        __syncthreads();
        if (t < RPB) sbuf[t] += x;
        __syncthreads();
    }
    if (t < RPB) {
        int ex = sbuf[t] - cnt[t];
        cur[t] = ex;
        if (r0 + t < r1) row_ptr[r0 + t] = lo + ex;
    }
    __syncthreads();
    for (int e = lo + t; e < hi; e += 256) {
        u64 p = packedA[e];
        int r = (int)((p >> 17) & 0x1FFFFu);
        int pos = lo + atomicAdd(&cur[r - r0], 1);
        edges[pos] = (u32)(((p >> 34) << 17) | (p & 0x1FFFFu));
    }
}

// ---------------- Horner SpMM on normalized fp8 states ----------------
// Zhat_l = X + (w[l+1]/w[l]) * A * Zhat_{l+1}   (WR 0 = fp8 state out, 2 = f32 final)
// final:  out = w0*X + w1 * A * Zhat_1
//
// Structure: one wave per TWO consecutive rows, 2 feats/lane (64 lanes = D).
// One uniform row_ptr read gives all 3 offsets; BOTH rows' 64-edge chunks are
// issued before any gather. Edge words broadcast via v_readlane (SGPR); gather
// = SGPR base + lane offset; 8-deep consume-as-you-go, 4+4 acc chains per row.
// (Established plateau: batch-16, two-bank pipelines, and SALU-stripped u64
// edges all land at 75-81 us/hop vs this kernel's 71 — per-CU outstanding-miss
// concurrency on random 128-B line gathers is the binding limit.)
template<int WR>
__global__ __launch_bounds__(256) void gpr_spmm(
    const int* __restrict__ row_ptr, const u32* __restrict__ edges,
    const void* __restrict__ Zold, const u16* __restrict__ Xbf,
    const float* __restrict__ Xf, const float* __restrict__ w, int l,
    void* __restrict__ Znew, float* __restrict__ out) {
    int pr = (int)(blockIdx.x * 4 + (threadIdx.x >> 6));
    pr = __builtin_amdgcn_readfirstlane(pr);
    if (pr >= N_NODES / 2) return;
    int row0 = pr * 2;
    int lane = threadIdx.x & 63;
    int s0 = __builtin_amdgcn_readfirstlane(row_ptr[row0]);
    int e0 = __builtin_amdgcn_readfirstlane(row_ptr[row0 + 1]);
    int e1 = __builtin_amdgcn_readfirstlane(row_ptr[row0 + 2]);
    int len0 = e0 - s0, len1 = e1 - e0;
    int m0 = (len0 < 64) ? len0 : 64;
    int m1 = (len1 < 64) ? len1 : 64;

    const u16* H8 = (const u16*)Zold;    // fp8 row-major: 2 fp8 feats per u16

    // issue both rows' first edge-chunks up-front (independent loads)
    u32 ew0 = 0, ew1 = 0;
    if (m0 > 0) { int tc = (lane < m0) ? lane : (m0 - 1); ew0 = edges[s0 + tc]; }
    if (m1 > 0) { int tc = (lane < m1) ? lane : (m1 - 1); ew1 = edges[e0 + tc]; }

    float ax[4] = {0.f,0.f,0.f,0.f}, ay[4] = {0.f,0.f,0.f,0.f};
    float bx[4] = {0.f,0.f,0.f,0.f}, by[4] = {0.f,0.f,0.f,0.f};

    #define PROC(EW, M, PX, PY)                                                 \
    for (int tt = 0; tt < (M); tt += 8) {                                       \
        _Pragma("unroll")                                                       \
        for (int j = 0; j < 8; ++j) {                                           \
            int t = tt + j;                    /* uniform, <= 63 */             \
            u32 es = (u32)__builtin_amdgcn_readlane((int)(EW), t);              \
            float v = (t < (M)) ? __uint_as_float((es >> 17) << 16) : 0.0f;     \
            u32 col = es & 0x1FFFFu;                                            \
            const u16* rp = H8 + (size_t)col * 64;                              \
            u32 h = rp[lane];                                                   \
            f32x2 f = __builtin_amdgcn_cvt_pk_f32_fp8(h, false);                \
            PX[j & 3] = fmaf(v, f[0], PX[j & 3]);                               \
            PY[j & 3] = fmaf(v, f[1], PY[j & 3]);                               \
        }                                                                       \
    }

    PROC(ew0, m0, ax, ay)
    // rare long-row chunks (P(len>64) ~ 0 at Poisson(32))
    for (int t0 = 64; t0 < len0; t0 += 64) {
        int rem = len0 - t0;
        int m = (rem < 64) ? rem : 64;
        int tc = (lane < m) ? lane : (m - 1);
        u32 ew = edges[s0 + t0 + tc];
        PROC(ew, m, ax, ay)
    }
    PROC(ew1, m1, bx, by)
    for (int t0 = 64; t0 < len1; t0 += 64) {
        int rem = len1 - t0;
        int m = (rem < 64) ? rem : 64;
        int tc = (lane < m) ? lane : (m - 1);
        u32 ew = edges[e0 + t0 + tc];
        PROC(ew, m, bx, by)
    }
    #undef PROC

    float axs = (ax[0] + ax[1]) + (ax[2] + ax[3]);
    float ays = (ay[0] + ay[1]) + (ay[2] + ay[3]);
    float bxs = (bx[0] + bx[1]) + (bx[2] + bx[3]);
    float bys = (by[0] + by[1]) + (by[2] + by[3]);
    if (!isfinite(axs)) axs = 0.0f;
    if (!isfinite(ays)) ays = 0.0f;
    if (!isfinite(bxs)) bxs = 0.0f;
    if (!isfinite(bys)) bys = 0.0f;

    size_t o0 = (size_t)row0 * 64 + lane;
    size_t o1 = o0 + 64;
    if (WR == 2) {
        float w0 = w[0], w1 = w[1];
        float2 xv0 = ((const float2*)Xf)[o0];
        float2 xv1 = ((const float2*)Xf)[o1];
        f32x2 r0, r1;
        r0[0] = fmaf(w1, axs, w0 * xv0.x);
        r0[1] = fmaf(w1, ays, w0 * xv0.y);
        r1[0] = fmaf(w1, bxs, w0 * xv1.x);
        r1[1] = fmaf(w1, bys, w0 * xv1.y);
        __builtin_nontemporal_store(r0, &((f32x2*)out)[o0]);
        __builtin_nontemporal_store(r1, &((f32x2*)out)[o1]);
    } else {
        float cc = w[l + 1] / w[l];
        u32 xb0 = __builtin_nontemporal_load((const u32*)Xbf + o0);
        u32 xb1 = __builtin_nontemporal_load((const u32*)Xbf + o1);
        float z0x = fmaf(cc, axs, bf2f(xb0 & 0xFFFFu));
        float z0y = fmaf(cc, ays, bf2f(xb0 >> 16));
        float z1x = fmaf(cc, bxs, bf2f(xb1 & 0xFFFFu));
        float z1y = fmaf(cc, bys, bf2f(xb1 >> 16));
        u32 p0 = __builtin_amdgcn_cvt_pk_fp8_f32(z0x, z0y, 0, false);
        u32 p1 = __builtin_amdgcn_cvt_pk_fp8_f32(z1x, z1y, 0, false);
        __builtin_nontemporal_store((u16)p0, (u16*)Znew + o0);
        __builtin_nontemporal_store((u16)p1, (u16*)Znew + o1);
    }
}

extern "C" void kernel_launch(void* const* d_in, const int* in_sizes, int n_in,
                              void* d_out, int out_size, void* d_ws, size_t ws_size,
                              hipStream_t stream) {
    const int*   erow  = (const int*)d_in[0];
    const int*   ecol  = (const int*)d_in[1];
    const float* evals = (const float*)d_in[2];
    const float* X     = (const float*)d_in[3];
    const float* w     = (const float*)d_in[4];
    float* out = (float*)d_out;

    const size_t n = (size_t)N_NODES * D_FEAT;  // 12.8M elements

    // workspace layout (~90 MB)
    char* base = (char*)d_ws;
    u8*  Za      = (u8*)base;                   // fp8, n bytes (init: Zhat_10 = fp8(X))
    u8*  Zb      = (u8*)(base + n);             // fp8, n bytes
    u16* Xbf     = (u16*)(base + 2 * n);        // bf16, 2n bytes
    u64* packedA = (u64*)(base + 4 * n);        // 3.2M u64 = 25.6 MB, dead after binB
    int* row_ptr = (int*)(base + 6 * n);        // 100001 (padded 100352)
    int* bucket_base   = row_ptr + 100352;
    int* bucket_cursor = bucket_base + 1024;
    int* bcount        = bucket_cursor + 1024;
    u32* edges   = (u32*)(bcount + 1024);       // 3.2M u32 = 12.8 MB

    dim3 b256(256);

    // CSR build
    hipMemsetAsync(bcount, 0, NBUCKETS * sizeof(int), stream);
    gpr_bucket_hist<<<dim3(512), b256, 0, stream>>>(erow, bcount);
    gpr_bucket_scan<<<dim3(1), dim3(1024), 0, stream>>>(bcount, bucket_base, bucket_cursor, row_ptr);
    gpr_binA<<<dim3(NA_BLOCKS), b256, 0, stream>>>(erow, ecol, evals, bucket_cursor, packedA);
    gpr_binB<<<dim3(NBUCKETS), b256, 0, stream>>>(bucket_base, packedA, row_ptr, edges);

    // Xbf = bf16(X), Za = fp8(X) = Zhat_10
    gpr_init<<<dim3((unsigned)((n / 4 + 255) / 256)), b256, 0, stream>>>(X, Xbf, Za, (int)(n / 4));

    dim3 spmm_grid((N_NODES / 2 + 3) / 4);      // 12500 blocks, 2 rows/wave
    // hops k = 9..1: fp8 -> fp8
    const void* Zold = Za;
    for (int k = L_FILTERS - 1; k >= 1; --k) {
        void* Znew = (Zold == (void*)Za) ? (void*)Zb : (void*)Za;
        gpr_spmm<0><<<spmm_grid, b256, 0, stream>>>(row_ptr, edges, Zold, Xbf, X, w, k, Znew, nullptr);
        Zold = Znew;
    }
    // hop k = 0 (final): fp8 -> fp32 out = w0*X + w1 * A * Zhat_1
    gpr_spmm<2><<<spmm_grid, b256, 0, stream>>>(row_ptr, edges, Zold, Xbf, X, w, 0, nullptr, out);
}